// Round 8
// baseline (125.166 us; speedup 1.0000x reference)
//
#include <hip/hip_runtime.h>
#include <cstddef>

// Problem: b=2,h=16,L=4096,d=16,dv=64, chunk=256. Second-order linear attn.
#define BH    32
#define LSEQ  4096
#define D     16
#define DV    64
#define CS    256
#define NC    16
#define NF    160     // padded feature dim (153 real)
#define NZ    65      // 64 v cols + z col
#define KSTEPS 5      // NF/32
#define PER   (NZ * NF)   // 10400 state elems per (bh, chunk)

typedef short short8 __attribute__((ext_vector_type(8)));
typedef float f32x4 __attribute__((ext_vector_type(4)));
typedef float f4 __attribute__((ext_vector_type(4)));
typedef unsigned uint4v __attribute__((ext_vector_type(4)));

// ws layout (bytes)
#define OFF_KBF 0u                                    // [BH][LSEQ][16] bf16  (4 MiB)
#define OFF_ST  (4u*1024u*1024u)                      // [BH][NC][NZ][NF] bf16 (10.65 MB)
#define OFF_VTG (OFF_ST + (unsigned)(BH*NC*PER*2))    // [BH][NZ][LSEQ] bf16 (17 MB, skewed)

__device__ __forceinline__ float bf2f(unsigned short u) {
  return __uint_as_float(((unsigned)u) << 16);
}
__device__ __forceinline__ short8 zero8() {
  short8 z = {0,0,0,0,0,0,0,0};
  return z;
}
// packed f32x2 -> bf16x2 (RNE), 1 VALU op
__device__ __forceinline__ unsigned cvtpk(float lo, float hi) {
  unsigned r;
  asm("v_cvt_pk_bf16_f32 %0, %1, %2" : "=v"(r) : "v"(lo), "v"(hi));
  return r;
}
__device__ __forceinline__ short8 pk4(unsigned a, unsigned b, unsigned c, unsigned d) {
  uint4v u = {a, b, c, d};
  return __builtin_bit_cast(short8, u);
}

// vt column skew: row f's data column j lives at (j + 8*((f>>2)&7)) mod 256.
// Breaks the transposed-staging bank conflict while keeping 16B-aligned b128
// reads legal. Row 64 (ones) has skew 0. The GLOBAL vtg image stores rows in
// this skewed layout verbatim (pass1 writes it, pass2 row-copies it back).
__device__ __forceinline__ int vtc(int f, int j) {
  return (j + (((f >> 2) & 7) << 3)) & 255;
}

// feature table: d | (e<<8) | (psi_half?1<<16:0).  qx/kx rows have [16]=1, [17]=0.
__device__ __forceinline__ unsigned feat_tbl(int f) {
  if (f == 0)  return 16u | (16u << 8);                       // const: 1*1
  if (f <= 16) return (unsigned)(f - 1) | (16u << 8);         // linear: x_d * 1
  if (f < 137) {                                              // pairs d<e
    int p = f - 17, off = 0;
    for (int d = 0; d < 15; ++d) {
      int cnt = 15 - d;
      if (p < off + cnt) return (unsigned)d | ((unsigned)(d + 1 + p - off) << 8);
      off += cnt;
    }
  }
  if (f < 153) {                                              // diag: psi=0.5*q_d^2, chi=k_d^2
    int d = f - 137;
    return (unsigned)d | ((unsigned)d << 8) | (1u << 16);
  }
  return 17u | (17u << 8);                                    // pad: 0*0
}

// ============ PASS 1: stage k (kbf) + v^T (vtg); compute state ============
// bh = blk & 31, c = blk >> 5  ->  blk % 8 == bh % 8: all chunks of a bh share
// an XCD, so kbf/st/vtg written here are L2-local for pass2's reads.
// c == 15: kbf + vtg only (its state is never consumed).
__global__ __launch_bounds__(512, 4) void pass1(const float* __restrict__ k,
                                                const float* __restrict__ v,
                                                unsigned* __restrict__ kbf_u32,
                                                unsigned* __restrict__ vtg,
                                                unsigned short* __restrict__ st) {
  __shared__ float kx[CS][18];
  __shared__ __align__(16) unsigned short vt[NZ][264];
  __shared__ unsigned tbl[NF];
  int blk = blockIdx.x, bh = blk & 31, c = blk >> 5;
  int t = threadIdx.x, w = t >> 6, lane = t & 63, quad = lane >> 4, n16 = lane & 15;
  const size_t base = (size_t)bh * LSEQ + (size_t)c * CS;
  (void)lane;

  {
    const f4* K4 = (const f4*)(k + base * D);
    uint2* kbd2 = (uint2*)(kbf_u32 + base * D / 2);
    for (int idx = t; idx < 1024; idx += 512) {
      f4 kv = K4[idx];
      kbd2[idx] = make_uint2(cvtpk(kv[0], kv[1]), cvtpk(kv[2], kv[3]));
      float* dst = &kx[idx >> 2][(idx & 3) * 4];
      *(float2*)dst = make_float2(kv[0], kv[1]);
      *(float2*)(dst + 2) = make_float2(kv[2], kv[3]);
    }
    for (int i = t; i < CS; i += 512) { kx[i][16] = 1.f; kx[i][17] = 0.f; }
  }
  {
    const f4* V4 = (const f4*)(v + base * DV);
    for (int idx = t; idx < 2048; idx += 512) {
      int m16 = idx & 15, j0 = (idx >> 4) * 2;
      f4 a  = V4[j0 * 16 + m16];
      f4 bq = V4[j0 * 16 + 16 + m16];
#pragma unroll
      for (int r = 0; r < 4; ++r)
        *(unsigned*)&vt[m16 * 4 + r][vtc(m16 * 4 + r, j0)] = cvtpk(a[r], bq[r]);
    }
    if (t < 128) ((unsigned*)&vt[64][0])[t] = 0x3F803F80u;       // ones row (skew 0)
  }
  if (t < NF) tbl[t] = feat_tbl(t);
  __syncthreads();

  // vtg copy-out (skewed rows verbatim): coalesced global, conflict-free LDS
  {
    unsigned* dst = vtg + (size_t)bh * NZ * (LSEQ / 2) + (size_t)c * (CS / 2);
    for (int i = t; i < NZ * (CS / 2); i += 512) {
      int f = i >> 7, j = i & 127;
      dst[(size_t)f * (LSEQ / 2) + j] = ((const unsigned*)&vt[f][0])[j];
    }
  }

  if (c < 15) {
    // waves 0,1 own feature-tiles {w, w+8}; waves 2..7 own tile {w}. (10 tiles)
    const int ntt = (w < 2) ? 2 : 1;
    unsigned short* stc = st + (size_t)(bh * NC + c) * PER;
    for (int tt = 0; tt < ntt; ++tt) {
      const int T = tt ? (w + 8) : w;
      unsigned tv = tbl[T * 16 + n16];
      int d0 = tv & 255, e0 = (tv >> 8) & 255;
      f32x4 acc5[5];
#pragma unroll
      for (int nt = 0; nt < 5; ++nt) acc5[nt] = (f32x4){0.f, 0.f, 0.f, 0.f};
      for (int jt = 0; jt < 8; ++jt) {
        float x[8];
#pragma unroll
        for (int i = 0; i < 8; ++i) {
          const float* kr = &kx[jt * 32 + quad * 8 + i][0];
          x[i] = kr[d0] * kr[e0];                        // chi (0.5 folded at store)
        }
        short8 afr = pk4(cvtpk(x[0], x[1]), cvtpk(x[2], x[3]),
                         cvtpk(x[4], x[5]), cvtpk(x[6], x[7]));
#pragma unroll
        for (int nt = 0; nt < 5; ++nt) {
          int ncol = nt * 16 + n16;
          short8 b = zero8();
          if (ncol < NZ)
            b = *(const short8*)(&vt[ncol][vtc(ncol, jt * 32 + quad * 8)]);
          acc5[nt] = __builtin_amdgcn_mfma_f32_16x16x32_bf16(afr, b, acc5[nt], 0, 0, 0);
        }
      }
      const int feat0 = T * 16 + quad * 4;
      float sc[4];
#pragma unroll
      for (int r = 0; r < 4; ++r)
        sc[r] = (feat0 + r >= 137 && feat0 + r < 153) ? 0.5f : 1.0f;  // psi-diag fold
#pragma unroll
      for (int nt = 0; nt < 5; ++nt) {
        int col = nt * 16 + n16;
        if (col < NZ) {
          unsigned lo = cvtpk(acc5[nt][0] * sc[0], acc5[nt][1] * sc[1]);
          unsigned hi = cvtpk(acc5[nt][2] * sc[2], acc5[nt][3] * sc[3]);
          *(uint2*)(stc + (size_t)col * NF + feat0) = make_uint2(lo, hi);
        }
      }
    }
  }
}

// ============ PASS 2: B (prefix) + inter + intra + epilogue ============
// R7 order: issue staging loads into REGISTERS -> run B (latency phases
// overlap) -> write staged regs + stt to LDS -> one barrier -> inter ->
// barrier -> intra -> epilogue. v never re-read; vt comes from pass1's vtg
// (L2-local verbatim row copy, no transpose, no cvt).
struct Smem2 {
  float qx[CS][18];                                     // 18432 B
  __align__(16) unsigned short vt[NZ][264];             // 34320 B
  union {
    __align__(16) unsigned short stt[NZ][168];          // 21840 B (B / inter)
    struct {
      __align__(16) unsigned short ptile[8][640];       // 10240 B (intra)
      float zline[CS];                                  // 1024 B (epilogue)
    } u;
  } b;
  unsigned tbl[NF];                                     // 640 B
};                                                      // total 75232 B

__global__ __launch_bounds__(512, 4) void pass2(const float* __restrict__ q,
                                                const unsigned short* __restrict__ kbf,
                                                const unsigned* __restrict__ vtg,
                                                const unsigned short* __restrict__ st,
                                                float* __restrict__ out) {
  __shared__ Smem2 sm;
  int blk = blockIdx.x, bh = blk & 31, c = blk >> 5;
  int t = threadIdx.x, w = t >> 6, lane = t & 63, quad = lane >> 4, n16 = lane & 15;
  const size_t base = (size_t)bh * LSEQ + (size_t)c * CS;

  // balanced strips: every wave gets (w/2+1) + ((15-w)/2+1) = 9 key-tiles
  const int s0 = w;
  const int s1 = 15 - w;

  // Q fragments: global -> registers (for intra QK^T)
  short8 qf[2] = {zero8(), zero8()};
  if (quad < 2) {
#pragma unroll
    for (int mm = 0; mm < 2; ++mm) {
      int s = mm ? s1 : s0;
      const f4* qp = (const f4*)(q + (base + (size_t)(s * 16 + n16)) * D + quad * 8);
      f4 qa = qp[0] * 0.25f;
      f4 qb = qp[1] * 0.25f;
      qf[mm] = pk4(cvtpk(qa[0], qa[1]), cvtpk(qa[2], qa[3]),
                   cvtpk(qb[0], qb[1]), cvtpk(qb[2], qb[3]));
    }
  }

  // ---- staging loads into registers (latency hides under B below) ----
  const f4* Q4 = (const f4*)(q + base * D);
  f4 qs0 = Q4[t];
  f4 qs1 = Q4[t + 512];
  const unsigned* vsrc = vtg + (size_t)bh * NZ * (LSEQ / 2) + (size_t)c * (CS / 2);
  unsigned vs[16];
#pragma unroll
  for (int i = 0; i < 16; ++i) {
    int idx = t + i * 512;
    vs[i] = vsrc[(size_t)(idx >> 7) * (LSEQ / 2) + (idx & 127)];
  }
  unsigned vtail = 0;
  if (t < 128) vtail = vsrc[(size_t)64 * (LSEQ / 2) + t];      // ones row (f=64)

  // ---------------- Phase B: pipelined prefix sum (registers only) -------------
  float sa0[8], sa1[8], sa2[8];
#pragma unroll
  for (int e = 0; e < 8; ++e) { sa0[e] = 0.f; sa1[e] = 0.f; sa2[e] = 0.f; }
  const int i0 = t * 8, i1 = i0 + 4096, i2 = i0 + 8192;
  const bool h2 = (i2 < PER);
  if (c > 0) {
    const unsigned short* stg = st + (size_t)bh * NC * PER;
    short8 a0 = *(const short8*)(stg + i0);
    short8 a1 = *(const short8*)(stg + i1);
    short8 a2 = h2 ? *(const short8*)(stg + i2) : zero8();
    for (int cc = 1; cc < c; ++cc) {
      const unsigned short* pn = stg + (size_t)cc * PER;
      short8 b0 = *(const short8*)(pn + i0);             // next-iter loads issued
      short8 b1 = *(const short8*)(pn + i1);             // before current adds
      short8 b2 = h2 ? *(const short8*)(pn + i2) : zero8();
#pragma unroll
      for (int e = 0; e < 8; ++e) {
        sa0[e] += bf2f((unsigned short)a0[e]);
        sa1[e] += bf2f((unsigned short)a1[e]);
        sa2[e] += bf2f((unsigned short)a2[e]);
      }
      a0 = b0; a1 = b1; a2 = b2;
    }
#pragma unroll
    for (int e = 0; e < 8; ++e) {
      sa0[e] += bf2f((unsigned short)a0[e]);
      sa1[e] += bf2f((unsigned short)a1[e]);
      sa2[e] += bf2f((unsigned short)a2[e]);
    }
  }

  // ---- write staged registers to LDS ----
  {
    f4 qv0 = qs0 * 0.25f;                                // d^-0.5
    float* d0p = &sm.qx[t >> 2][(t & 3) * 4];
    *(float2*)d0p = make_float2(qv0[0], qv0[1]);
    *(float2*)(d0p + 2) = make_float2(qv0[2], qv0[3]);
    int t1 = t + 512;
    f4 qv1 = qs1 * 0.25f;
    float* d1p = &sm.qx[t1 >> 2][(t1 & 3) * 4];
    *(float2*)d1p = make_float2(qv1[0], qv1[1]);
    *(float2*)(d1p + 2) = make_float2(qv1[2], qv1[3]);
    if (t < CS) { sm.qx[t][16] = 1.f; sm.qx[t][17] = 0.f; }
#pragma unroll
    for (int i = 0; i < 16; ++i) {
      int idx = t + i * 512;
      ((unsigned*)&sm.vt[idx >> 7][0])[idx & 127] = vs[i];
    }
    if (t < 128) ((unsigned*)&sm.vt[64][0])[t] = vtail;
    if (t < NF) sm.tbl[t] = feat_tbl(t);
  }
  // stt write (disjoint LDS region; own-thread data, so pre-barrier is fine)
  if (c > 0) {
    int col = i0 / NF, ft = i0 - col * NF;
    *(short8*)(&sm.b.stt[col][ft]) =
        pk4(cvtpk(sa0[0], sa0[1]), cvtpk(sa0[2], sa0[3]),
            cvtpk(sa0[4], sa0[5]), cvtpk(sa0[6], sa0[7]));
    col = i1 / NF; ft = i1 - col * NF;
    *(short8*)(&sm.b.stt[col][ft]) =
        pk4(cvtpk(sa1[0], sa1[1]), cvtpk(sa1[2], sa1[3]),
            cvtpk(sa1[4], sa1[5]), cvtpk(sa1[6], sa1[7]));
    if (h2) {
      col = i2 / NF; ft = i2 - col * NF;
      *(short8*)(&sm.b.stt[col][ft]) =
          pk4(cvtpk(sa2[0], sa2[1]), cvtpk(sa2[2], sa2[3]),
              cvtpk(sa2[4], sa2[5]), cvtpk(sa2[6], sa2[7]));
    }
  }
  __syncthreads();

  // ---------------- inter: acc += psi(Q) · S_prefix ----------------
  f32x4 accC[2][5];
#pragma unroll
  for (int mm = 0; mm < 2; ++mm)
#pragma unroll
    for (int nt = 0; nt < 5; ++nt) accC[mm][nt] = (f32x4){0.f, 0.f, 0.f, 0.f};

  if (c > 0) {
    const float* qrow0 = &sm.qx[s0 * 16 + n16][0];
    const float* qrow1 = &sm.qx[s1 * 16 + n16][0];
    for (int ks = 0; ks < KSTEPS; ++ks) {
      unsigned tvv[8];
#pragma unroll
      for (int i = 0; i < 8; ++i) tvv[i] = sm.tbl[ks * 32 + quad * 8 + i];
      float x0[8], x1[8];
#pragma unroll
      for (int i = 0; i < 8; ++i) {
        int d = tvv[i] & 255, e = (tvv[i] >> 8) & 255;
        x0[i] = qrow0[d] * qrow0[e];
        x1[i] = qrow1[d] * qrow1[e];
      }
      short8 afr0 = pk4(cvtpk(x0[0], x0[1]), cvtpk(x0[2], x0[3]),
                        cvtpk(x0[4], x0[5]), cvtpk(x0[6], x0[7]));
      short8 afr1 = pk4(cvtpk(x1[0], x1[1]), cvtpk(x1[2], x1[3]),
                        cvtpk(x1[4], x1[5]), cvtpk(x1[6], x1[7]));
#pragma unroll
      for (int nt = 0; nt < 5; ++nt) {
        int ncol = nt * 16 + n16;
        short8 b = zero8();
        if (ncol < NZ) b = *(const short8*)(&sm.b.stt[ncol][ks * 32 + quad * 8]);
        accC[0][nt] = __builtin_amdgcn_mfma_f32_16x16x32_bf16(afr0, b, accC[0][nt], 0, 0, 0);
        accC[1][nt] = __builtin_amdgcn_mfma_f32_16x16x32_bf16(afr1, b, accC[1][nt], 0, 0, 0);
      }
    }
  }
  __syncthreads();   // stt fully consumed -> ptile/zline may alias it

  // ---------------- intra: balanced strips; K-frags from kbf (L2-local) --------
  const unsigned short* kbc = kbf + base * D;
  unsigned short* pw = &sm.b.u.ptile[w][0];

#pragma unroll
  for (int mm = 0; mm < 2; ++mm) {
    const int s = mm ? s1 : s0;
    const int ntiles = (s >> 1) + 1;
    for (int jt = 0; jt < ntiles; ++jt) {
      short8 kb[2];
#pragma unroll
      for (int ntk = 0; ntk < 2; ++ntk) {
        short8 b = zero8();
        if (quad < 2)
          b = *(const short8*)(kbc + (size_t)(jt * 32 + ntk * 16 + n16) * D + quad * 8);
        kb[ntk] = b;
      }
      f32x4 zf = (f32x4){0.f, 0.f, 0.f, 0.f};
      f32x4 sres[2];
      sres[0] = __builtin_amdgcn_mfma_f32_16x16x32_bf16(qf[mm], kb[0], zf, 0, 0, 0);
      sres[1] = __builtin_amdgcn_mfma_f32_16x16x32_bf16(qf[mm], kb[1], zf, 0, 0, 0);
      const bool last = (jt == ntiles - 1);
#pragma unroll
      for (int ntk = 0; ntk < 2; ++ntk) {
        float ph[4];
#pragma unroll
        for (int r = 0; r < 4; ++r) {
          float sv = sres[ntk][r];
          float phi = fmaf(sv, fmaf(0.5f, sv, 1.0f), 1.0f);  // 1 + s + 0.5 s^2
          if (last) {
            int qrow_g = s * 16 + quad * 4 + r;
            int kcol_g = jt * 32 + ntk * 16 + n16;
            if (kcol_g > qrow_g) phi = 0.f;                  // causal
          }
          ph[r] = phi;
        }
        unsigned u01 = cvtpk(ph[0], ph[1]);
        unsigned u23 = cvtpk(ph[2], ph[3]);
        int rb = (quad * 4) * 40 + ntk * 16 + n16;
        pw[rb      ] = (unsigned short)u01;
        pw[rb +  40] = (unsigned short)(u01 >> 16);
        pw[rb +  80] = (unsigned short)u23;
        pw[rb + 120] = (unsigned short)(u23 >> 16);
      }
      short8 pa = *(const short8*)(pw + n16 * 40 + quad * 8);
#pragma unroll
      for (int nt = 0; nt < 5; ++nt) {
        int ncol = nt * 16 + n16;
        short8 b = zero8();
        if (ncol < NZ)
          b = *(const short8*)(&sm.vt[ncol][vtc(ncol, jt * 32 + quad * 8)]);
        accC[mm][nt] = __builtin_amdgcn_mfma_f32_16x16x32_bf16(pa, b, accC[mm][nt], 0, 0, 0);
      }
    }
  }

  // epilogue: z broadcast via per-wave LDS rows, normalize, store
  if (n16 == 0) {
#pragma unroll
    for (int mm = 0; mm < 2; ++mm) {
      int s = mm ? s1 : s0;
#pragma unroll
      for (int r = 0; r < 4; ++r)
        sm.b.u.zline[s * 16 + quad * 4 + r] = accC[mm][4][r];
    }
  }
  float* oc = out + base * DV;
#pragma unroll
  for (int mm = 0; mm < 2; ++mm) {
    int s = mm ? s1 : s0;
#pragma unroll
    for (int r = 0; r < 4; ++r) {
      int qrow = s * 16 + quad * 4 + r;
      float inv = __builtin_amdgcn_rcpf(sm.b.u.zline[qrow] + 1e-6f);
#pragma unroll
      for (int nt = 0; nt < 4; ++nt)
        oc[(size_t)qrow * DV + nt * 16 + n16] = accC[mm][nt][r] * inv;
    }
  }
}

extern "C" void kernel_launch(void* const* d_in, const int* in_sizes, int n_in,
                              void* d_out, int out_size, void* d_ws, size_t ws_size,
                              hipStream_t stream) {
  (void)in_sizes; (void)n_in; (void)out_size; (void)ws_size;
  const float* q = (const float*)d_in[0];
  const float* k = (const float*)d_in[1];
  const float* v = (const float*)d_in[2];
  float* out = (float*)d_out;
  char* wsb = (char*)d_ws;
  unsigned*       kbf32 = (unsigned*)(wsb + OFF_KBF);
  unsigned short* kbf   = (unsigned short*)(wsb + OFF_KBF);
  unsigned short* stp   = (unsigned short*)(wsb + OFF_ST);
  unsigned*       vtg   = (unsigned*)(wsb + OFF_VTG);

  pass1<<<BH * NC, 512, 0, stream>>>(k, v, kbf32, vtg, stp);
  pass2<<<BH * NC, 512, 0, stream>>>(q, kbf, vtg, stp, out);
}